// Round 1
// baseline (444.657 us; speedup 1.0000x reference)
//
#include <hip/hip_runtime.h>
#include <hip/hip_bf16.h>

// TriangleMultiplicativeModule (ingoing) — B=1, N=512, D=H=128
// Pipeline: LN1 -> 5 projections (+mask+sigmoid gates) -> per-channel einsum
//           -> LN2*gate -> output projection.
// All GEMMs in bf16 MFMA (16x16x32), fp32 accumulate.

#define NSEQ 512
#define NN 262144        // 512*512
#define DMODEL 128

typedef __attribute__((ext_vector_type(8))) short short8;
typedef __attribute__((ext_vector_type(4))) float f32x4;

__device__ __forceinline__ unsigned short f2b(float f) {
    __hip_bfloat16 h = __float2bfloat16(f);
    return *reinterpret_cast<unsigned short*>(&h);
}
__device__ __forceinline__ float b2f(unsigned short u) {
    __hip_bfloat16 h;
    *reinterpret_cast<unsigned short*>(&h) = u;
    return __bfloat162float(h);
}
__device__ __forceinline__ float sigmoidf_(float x) {
    return 1.0f / (1.0f + __expf(-x));
}

// ---------------------------------------------------------------------------
// Weight transpose + bf16 cast: w[k][h] (fp32, 128x128) -> wt[h][k] (bf16)
// ---------------------------------------------------------------------------
__global__ __launch_bounds__(256) void k_wt(const float* __restrict__ w,
                                            unsigned short* __restrict__ wt) {
    int idx = blockIdx.x * 256 + threadIdx.x;   // 0..16383
    int d = idx >> 7, h = idx & 127;
    wt[h * 128 + d] = f2b(w[idx]);
}

// ---------------------------------------------------------------------------
// LN1 over D=128 + bf16 cast. One wave per row, float2 per lane.
// ---------------------------------------------------------------------------
__global__ __launch_bounds__(256) void k_ln1(const float* __restrict__ x,
                                             const float* __restrict__ sc,
                                             const float* __restrict__ bi,
                                             unsigned short* __restrict__ xn) {
    int wave = threadIdx.x >> 6;
    int lane = threadIdx.x & 63;
    size_t r = (size_t)blockIdx.x * 4 + wave;       // 262144 rows
    const float* px = x + r * DMODEL + lane * 2;
    float2 v = *(const float2*)px;
    float s = v.x + v.y;
    float sq = v.x * v.x + v.y * v.y;
    for (int m = 1; m < 64; m <<= 1) {
        s  += __shfl_xor(s, m);
        sq += __shfl_xor(sq, m);
    }
    float mean = s * (1.f / 128.f);
    float var  = sq * (1.f / 128.f) - mean * mean;
    float inv  = rsqrtf(var + 1e-6f);
    float2 scv = *(const float2*)(sc + lane * 2);
    float2 biv = *(const float2*)(bi + lane * 2);
    unsigned int o0 = f2b((v.x - mean) * inv * scv.x + biv.x);
    unsigned int o1 = f2b((v.y - mean) * inv * scv.y + biv.y);
    *(unsigned int*)(xn + r * DMODEL + lane * 2) = o0 | (o1 << 16);
}

// ---------------------------------------------------------------------------
// Projection GEMM. Block tile: 64 rows (r = a*512+b, a varying, b fixed) x 128 h.
// Loops over 5 weight matrices in LDS; epilogue fuses bias, mask, sigmoid and
// writes left_t/right_t in transposed [h][i=b][k=a] layout (a contiguous -> 8B packs).
// ---------------------------------------------------------------------------
__global__ __launch_bounds__(256) void k_proj(
    const unsigned short* __restrict__ xn,
    const float* __restrict__ src_mask,
    const unsigned short* __restrict__ wt,  // wl_t, wlg_t, wr_t, wrg_t, wog_t (16384 each)
    const float* __restrict__ bl,  const float* __restrict__ blg,
    const float* __restrict__ br,  const float* __restrict__ brg,
    const float* __restrict__ bog,
    unsigned short* __restrict__ left_t,
    unsigned short* __restrict__ right_t,
    unsigned short* __restrict__ og) {
    __shared__ __align__(16) unsigned short As[64 * 136];
    __shared__ __align__(16) unsigned short Bs[128 * 136];
    const int t = threadIdx.x;
    const int lane = t & 63;
    const int wv = t >> 6;
    const int a0 = blockIdx.x * 64;
    const int b  = blockIdx.y;
    const int n0 = wv * 32;

    // stage A: 64 rows (stride-512 in row space) x 128 k
    for (int it = 0; it < 4; ++it) {
        int idx = it * 256 + t;
        int row = idx >> 4, c = idx & 15;
        *(short8*)(&As[row * 136 + c * 8]) =
            *(const short8*)(xn + ((size_t)(a0 + row) * NSEQ + b) * DMODEL + c * 8);
    }

    f32x4 acc0[4][2], acc1[4][2];
    float smb = src_mask[b];

    for (int pair = 0; pair < 3; ++pair) {
        int nmat = (pair == 2) ? 1 : 2;
        for (int m = 0; m < nmat; ++m) {
            int mat = pair * 2 + m;   // 0=wl 1=wlg 2=wr 3=wrg 4=wog
            __syncthreads();          // previous compute done reading Bs
            const unsigned short* wsrc = wt + mat * 16384;
            for (int it = 0; it < 8; ++it) {
                int idx = it * 256 + t;
                int h = idx >> 4, c = idx & 15;
                *(short8*)(&Bs[h * 136 + c * 8]) = *(const short8*)(wsrc + h * 128 + c * 8);
            }
            __syncthreads();
            f32x4(*acc)[2] = m ? acc1 : acc0;
            for (int mf = 0; mf < 4; ++mf)
                for (int nf = 0; nf < 2; ++nf)
                    acc[mf][nf] = f32x4{0.f, 0.f, 0.f, 0.f};
            for (int kc = 0; kc < 4; ++kc) {
                int ko = kc * 32 + (lane >> 4) * 8;
                short8 af[4], bf[2];
                for (int mf = 0; mf < 4; ++mf)
                    af[mf] = *(const short8*)(&As[(mf * 16 + (lane & 15)) * 136 + ko]);
                for (int nf = 0; nf < 2; ++nf)
                    bf[nf] = *(const short8*)(&Bs[(n0 + nf * 16 + (lane & 15)) * 136 + ko]);
                for (int mf = 0; mf < 4; ++mf)
                    for (int nf = 0; nf < 2; ++nf)
                        acc[mf][nf] = __builtin_amdgcn_mfma_f32_16x16x32_bf16(
                            af[mf], bf[nf], acc[mf][nf], 0, 0, 0);
            }
        }
        if (pair < 2) {
            const float* b1 = (pair == 0) ? bl : br;
            const float* b2 = (pair == 0) ? blg : brg;
            unsigned short* dst = (pair == 0) ? left_t : right_t;
            for (int nf = 0; nf < 2; ++nf) {
                int h = n0 + nf * 16 + (lane & 15);
                float b1v = b1[h], b2v = b2[h];
                for (int mf = 0; mf < 4; ++mf) {
                    int abase = a0 + mf * 16 + ((lane >> 4) << 2);
                    unsigned long long pv64 = 0;
                    for (int j = 0; j < 4; ++j) {
                        float pv = acc0[mf][nf][j] + b1v;
                        float gv = acc1[mf][nf][j] + b2v;
                        float mk = src_mask[abase + j] * smb;
                        unsigned long long q = f2b(pv * mk * sigmoidf_(gv));
                        pv64 |= q << (16 * j);
                    }
                    *(unsigned long long*)(dst + (size_t)h * NN + (size_t)b * NSEQ + abase) = pv64;
                }
            }
        } else {
            for (int nf = 0; nf < 2; ++nf) {
                int h = n0 + nf * 16 + (lane & 15);
                float bv = bog[h];
                for (int mf = 0; mf < 4; ++mf) {
                    int abase = a0 + mf * 16 + ((lane >> 4) << 2);
                    for (int j = 0; j < 4; ++j) {
                        float ov = sigmoidf_(acc0[mf][nf][j] + bv);
                        og[((size_t)(abase + j) * NSEQ + b) * DMODEL + h] = f2b(ov);
                    }
                }
            }
        }
    }
}

// ---------------------------------------------------------------------------
// Einsum: per d-plane GEMM C[i][j] = sum_k A[i][k]*B[j][k], 128x128 tile, BK=32.
// ---------------------------------------------------------------------------
__global__ __launch_bounds__(256) void k_einsum(
    const unsigned short* __restrict__ lt,
    const unsigned short* __restrict__ rt,
    unsigned short* __restrict__ mid) {
    __shared__ __align__(16) unsigned short As[128 * 40];
    __shared__ __align__(16) unsigned short Bs[128 * 40];
    const int t = threadIdx.x, lane = t & 63, wv = t >> 6;
    const int d = blockIdx.z;
    const int i0 = blockIdx.x * 128, j0 = blockIdx.y * 128;
    const int m0 = (wv >> 1) * 64, n0 = (wv & 1) * 64;
    const unsigned short* Ag = lt + (size_t)d * NN;
    const unsigned short* Bg = rt + (size_t)d * NN;

    f32x4 acc[4][4];
    for (int mf = 0; mf < 4; ++mf)
        for (int nf = 0; nf < 4; ++nf)
            acc[mf][nf] = f32x4{0.f, 0.f, 0.f, 0.f};

    for (int k0 = 0; k0 < NSEQ; k0 += 32) {
        __syncthreads();    // protect previous iteration's fragment reads
        for (int it = 0; it < 2; ++it) {
            int idx = it * 256 + t;
            int row = idx >> 2, c = idx & 3;
            *(short8*)(&As[row * 40 + c * 8]) =
                *(const short8*)(Ag + (size_t)(i0 + row) * NSEQ + k0 + c * 8);
            *(short8*)(&Bs[row * 40 + c * 8]) =
                *(const short8*)(Bg + (size_t)(j0 + row) * NSEQ + k0 + c * 8);
        }
        __syncthreads();
        int ko = (lane >> 4) * 8;
        short8 af[4], bf[4];
        for (int mf = 0; mf < 4; ++mf)
            af[mf] = *(const short8*)(&As[(m0 + mf * 16 + (lane & 15)) * 40 + ko]);
        for (int nf = 0; nf < 4; ++nf)
            bf[nf] = *(const short8*)(&Bs[(n0 + nf * 16 + (lane & 15)) * 40 + ko]);
        for (int mf = 0; mf < 4; ++mf)
            for (int nf = 0; nf < 4; ++nf)
                acc[mf][nf] = __builtin_amdgcn_mfma_f32_16x16x32_bf16(
                    af[mf], bf[nf], acc[mf][nf], 0, 0, 0);
    }
    unsigned short* out = mid + (size_t)d * NN;
    for (int mf = 0; mf < 4; ++mf) {
        int rbase = i0 + m0 + mf * 16 + ((lane >> 4) << 2);
        for (int nf = 0; nf < 4; ++nf) {
            int col = j0 + n0 + nf * 16 + (lane & 15);
            for (int j = 0; j < 4; ++j)
                out[(size_t)(rbase + j) * NSEQ + col] = f2b(acc[mf][nf][j]);
        }
    }
}

// ---------------------------------------------------------------------------
// LN2 over H (strided d-plane reads) * out_gate -> g (bf16). Thread per position.
// ---------------------------------------------------------------------------
__global__ __launch_bounds__(256) void k_ln2gate(
    const unsigned short* __restrict__ mid,
    const unsigned short* __restrict__ og,
    const float* __restrict__ sc, const float* __restrict__ bi,
    unsigned short* __restrict__ g) {
    size_t p = (size_t)blockIdx.x * 256 + threadIdx.x;
    float s = 0.f, sq = 0.f;
    for (int dd = 0; dd < 128; ++dd) {
        float v = b2f(mid[(size_t)dd * NN + p]);
        s += v; sq += v * v;
    }
    float mean = s * (1.f / 128.f);
    float var  = sq * (1.f / 128.f) - mean * mean;
    float inv  = rsqrtf(var + 1e-6f);
    for (int c = 0; c < 16; ++c) {
        short8 ov = *(const short8*)(og + p * DMODEL + c * 8);
        short8 r8;
        for (int e = 0; e < 8; ++e) {
            int dd = c * 8 + e;
            float v = b2f(mid[(size_t)dd * NN + p]);  // L2 re-read
            float y = (v - mean) * inv * sc[dd] + bi[dd];
            float gate = b2f((unsigned short)ov[e]);   // sigmoid already applied
            r8[e] = (short)f2b(y * gate);
        }
        *(short8*)(g + p * DMODEL + c * 8) = r8;
    }
}

// ---------------------------------------------------------------------------
// Output projection: out = g @ wo + bo (fp32 out). 64-row tiles, full N=128.
// ---------------------------------------------------------------------------
__global__ __launch_bounds__(256) void k_out(
    const unsigned short* __restrict__ g,
    const unsigned short* __restrict__ wt_o,
    const float* __restrict__ bo,
    float* __restrict__ out) {
    __shared__ __align__(16) unsigned short As[64 * 136];
    __shared__ __align__(16) unsigned short Bs[128 * 136];
    const int t = threadIdx.x, lane = t & 63, wv = t >> 6;
    const size_t r0 = (size_t)blockIdx.x * 64;
    const int n0 = wv * 32;
    for (int it = 0; it < 4; ++it) {
        int idx = it * 256 + t;
        int row = idx >> 4, c = idx & 15;
        *(short8*)(&As[row * 136 + c * 8]) =
            *(const short8*)(g + (r0 + row) * DMODEL + c * 8);
    }
    for (int it = 0; it < 8; ++it) {
        int idx = it * 256 + t;
        int h = idx >> 4, c = idx & 15;
        *(short8*)(&Bs[h * 136 + c * 8]) = *(const short8*)(wt_o + h * 128 + c * 8);
    }
    __syncthreads();
    f32x4 acc[4][2];
    for (int mf = 0; mf < 4; ++mf)
        for (int nf = 0; nf < 2; ++nf)
            acc[mf][nf] = f32x4{0.f, 0.f, 0.f, 0.f};
    for (int kc = 0; kc < 4; ++kc) {
        int ko = kc * 32 + (lane >> 4) * 8;
        short8 af[4], bf[2];
        for (int mf = 0; mf < 4; ++mf)
            af[mf] = *(const short8*)(&As[(mf * 16 + (lane & 15)) * 136 + ko]);
        for (int nf = 0; nf < 2; ++nf)
            bf[nf] = *(const short8*)(&Bs[(n0 + nf * 16 + (lane & 15)) * 136 + ko]);
        for (int mf = 0; mf < 4; ++mf)
            for (int nf = 0; nf < 2; ++nf)
                acc[mf][nf] = __builtin_amdgcn_mfma_f32_16x16x32_bf16(
                    af[mf], bf[nf], acc[mf][nf], 0, 0, 0);
    }
    for (int nf = 0; nf < 2; ++nf) {
        int n = n0 + nf * 16 + (lane & 15);
        float bv = bo[n];
        for (int mf = 0; mf < 4; ++mf) {
            int rb = mf * 16 + ((lane >> 4) << 2);
            for (int j = 0; j < 4; ++j)
                out[(r0 + rb + j) * DMODEL + n] = acc[mf][nf][j] + bv;
        }
    }
}

// ---------------------------------------------------------------------------
extern "C" void kernel_launch(void* const* d_in, const int* in_sizes, int n_in,
                              void* d_out, int out_size, void* d_ws, size_t ws_size,
                              hipStream_t stream) {
    const float* x    = (const float*)d_in[0];
    const float* sm   = (const float*)d_in[1];
    const float* ln1s = (const float*)d_in[2];
    const float* ln1b = (const float*)d_in[3];
    const float* wl   = (const float*)d_in[4];
    const float* bl   = (const float*)d_in[5];
    const float* wr   = (const float*)d_in[6];
    const float* br   = (const float*)d_in[7];
    const float* wlg  = (const float*)d_in[8];
    const float* blg  = (const float*)d_in[9];
    const float* wrg  = (const float*)d_in[10];
    const float* brg  = (const float*)d_in[11];
    const float* wog  = (const float*)d_in[12];
    const float* bog  = (const float*)d_in[13];
    const float* ln2s = (const float*)d_in[14];
    const float* ln2b = (const float*)d_in[15];
    const float* wo   = (const float*)d_in[16];
    const float* bo   = (const float*)d_in[17];
    float* out = (float*)d_out;

    // workspace layout (bytes):
    //   wt  @ 0        : 6 x 16384 bf16   (196608 B)
    //   xn  @ 196608   : 64 MB  (reused as g after einsum)
    //   lt  @ +64MB, rt @ +128MB, og @ +192MB, mid @ +256MB   -> total ~320.2 MB
    char* ws = (char*)d_ws;
    unsigned short* wt  = (unsigned short*)ws;
    unsigned short* xn  = (unsigned short*)(ws + 196608);
    unsigned short* lt  = (unsigned short*)(ws + 196608 + 1ull * 67108864);
    unsigned short* rt  = (unsigned short*)(ws + 196608 + 2ull * 67108864);
    unsigned short* ogb = (unsigned short*)(ws + 196608 + 3ull * 67108864);
    unsigned short* mid = (unsigned short*)(ws + 196608 + 4ull * 67108864);
    unsigned short* gbuf = xn;  // reuse: xn dead after k_proj

    k_wt<<<64, 256, 0, stream>>>(wl,  wt + 0 * 16384);
    k_wt<<<64, 256, 0, stream>>>(wlg, wt + 1 * 16384);
    k_wt<<<64, 256, 0, stream>>>(wr,  wt + 2 * 16384);
    k_wt<<<64, 256, 0, stream>>>(wrg, wt + 3 * 16384);
    k_wt<<<64, 256, 0, stream>>>(wog, wt + 4 * 16384);
    k_wt<<<64, 256, 0, stream>>>(wo,  wt + 5 * 16384);
    k_ln1<<<65536, 256, 0, stream>>>(x, ln1s, ln1b, xn);
    k_proj<<<dim3(8, 512), 256, 0, stream>>>(xn, sm, wt, bl, blg, br, brg, bog, lt, rt, ogb);
    k_einsum<<<dim3(4, 4, 128), 256, 0, stream>>>(lt, rt, mid);
    k_ln2gate<<<1024, 256, 0, stream>>>(mid, ogb, ln2s, ln2b, gbuf);
    k_out<<<4096, 256, 0, stream>>>(gbuf, wt + 5 * 16384, bo, out);
}

// Round 2
// 358.792 us; speedup vs baseline: 1.2393x; 1.2393x over previous
//
#include <hip/hip_runtime.h>
#include <hip/hip_bf16.h>

// TriangleMultiplicativeModule (ingoing) — B=1, N=512, D=H=128
// R2: LN1 fused into proj; weights direct global->VGPR (no Bs LDS);
//     ln2gate single-pass (row in regs) + LDS-staged coalesced output.

#define NSEQ 512
#define NN 262144        // 512*512
#define DMODEL 128

typedef __attribute__((ext_vector_type(8))) short short8;
typedef __attribute__((ext_vector_type(4))) float f32x4;

__device__ __forceinline__ unsigned short f2b(float f) {
    __hip_bfloat16 h = __float2bfloat16(f);
    return *reinterpret_cast<unsigned short*>(&h);
}
__device__ __forceinline__ float b2f(unsigned short u) {
    __hip_bfloat16 h;
    *reinterpret_cast<unsigned short*>(&h) = u;
    return __bfloat162float(h);
}
__device__ __forceinline__ float sigmoidf_(float x) {
    return 1.0f / (1.0f + __expf(-x));
}

// ---------------------------------------------------------------------------
// All 6 weight transposes in one launch: w[k][h] fp32 -> wt[mat][h][k] bf16
// ---------------------------------------------------------------------------
__global__ __launch_bounds__(256) void k_wt_all(
    const float* __restrict__ w0, const float* __restrict__ w1,
    const float* __restrict__ w2, const float* __restrict__ w3,
    const float* __restrict__ w4, const float* __restrict__ w5,
    unsigned short* __restrict__ wt) {
    int bid = blockIdx.x;
    int mat = bid >> 6;
    const float* w = (mat == 0) ? w0 : (mat == 1) ? w1 : (mat == 2) ? w2
                   : (mat == 3) ? w3 : (mat == 4) ? w4 : w5;
    int idx = (bid & 63) * 256 + threadIdx.x;   // 0..16383
    int d = idx >> 7, h = idx & 127;
    wt[mat * 16384 + h * 128 + d] = f2b(w[idx]);
}

// ---------------------------------------------------------------------------
// Fused LN1 + 5 projections. Block: 64 rows (r = a*512+b, a varying) x 128 h.
// LN1 computed in-register during A staging (4 threads/row, shfl reduce).
// A-fragments hoisted to VGPRs once; weights loaded direct global->VGPR
// (L2/L3-resident, 160KB total), double-buffered one matrix ahead.
// ---------------------------------------------------------------------------
__global__ __launch_bounds__(256) void k_proj(
    const float* __restrict__ x,
    const float* __restrict__ src_mask,
    const float* __restrict__ ln1s, const float* __restrict__ ln1b,
    const unsigned short* __restrict__ wt,  // wl,wlg,wr,wrg,wog (16384 each)
    const float* __restrict__ bl,  const float* __restrict__ blg,
    const float* __restrict__ br,  const float* __restrict__ brg,
    const float* __restrict__ bog,
    unsigned short* __restrict__ left_t,
    unsigned short* __restrict__ right_t,
    unsigned short* __restrict__ og) {
    __shared__ __align__(16) unsigned short As[64 * 136];
    const int t = threadIdx.x;
    const int lane = t & 63;
    const int wv = t >> 6;
    const int a0 = blockIdx.x * 64;
    const int b  = blockIdx.y;
    const int n0 = wv * 32;

    // ---- LN1 stage: 4 threads per row, 32 fp32 each ----
    {
        int row = t >> 2, seg = t & 3;
        const float* px = x + ((size_t)(a0 + row) * NSEQ + b) * DMODEL + seg * 32;
        float4 xv[8];
        float s = 0.f, sq = 0.f;
        #pragma unroll
        for (int i = 0; i < 8; ++i) {
            xv[i] = *(const float4*)(px + i * 4);
            s  += xv[i].x + xv[i].y + xv[i].z + xv[i].w;
            sq += xv[i].x * xv[i].x + xv[i].y * xv[i].y
                + xv[i].z * xv[i].z + xv[i].w * xv[i].w;
        }
        s  += __shfl_xor(s, 1);  s  += __shfl_xor(s, 2);
        sq += __shfl_xor(sq, 1); sq += __shfl_xor(sq, 2);
        float mean = s * (1.f / 128.f);
        float var  = sq * (1.f / 128.f) - mean * mean;
        float inv  = rsqrtf(var + 1e-6f);
        #pragma unroll
        for (int v = 0; v < 4; ++v) {
            short8 o;
            #pragma unroll
            for (int e = 0; e < 8; ++e) {
                int d = seg * 32 + v * 8 + e;
                float xe = ((const float*)&xv[v * 2 + (e >> 2)])[e & 3];
                o[e] = (short)f2b((xe - mean) * inv * ln1s[d] + ln1b[d]);
            }
            *(short8*)(&As[row * 136 + seg * 32 + v * 8]) = o;
        }
    }
    __syncthreads();

    // ---- A fragments -> registers (shared across all 5 matrices) ----
    short8 af[4][4];   // [mf][kc]
    #pragma unroll
    for (int mf = 0; mf < 4; ++mf)
        #pragma unroll
        for (int kc = 0; kc < 4; ++kc)
            af[mf][kc] = *(const short8*)(
                &As[(mf * 16 + (lane & 15)) * 136 + kc * 32 + (lane >> 4) * 8]);

    short8 bfA[2][4], bfB[2][4];
    f32x4 acc0[4][2], acc1[4][2];
    float smb = src_mask[b];

    auto loadB = [&](short8 (&dst)[2][4], int mat) {
        #pragma unroll
        for (int nf = 0; nf < 2; ++nf)
            #pragma unroll
            for (int kc = 0; kc < 4; ++kc)
                dst[nf][kc] = *(const short8*)(
                    wt + mat * 16384 + (n0 + nf * 16 + (lane & 15)) * 128
                       + kc * 32 + (lane >> 4) * 8);
    };
    auto mmat = [&](f32x4 (&acc)[4][2], short8 (&bf)[2][4]) {
        #pragma unroll
        for (int mf = 0; mf < 4; ++mf)
            #pragma unroll
            for (int nf = 0; nf < 2; ++nf)
                acc[mf][nf] = f32x4{0.f, 0.f, 0.f, 0.f};
        #pragma unroll
        for (int kc = 0; kc < 4; ++kc)
            #pragma unroll
            for (int mf = 0; mf < 4; ++mf)
                #pragma unroll
                for (int nf = 0; nf < 2; ++nf)
                    acc[mf][nf] = __builtin_amdgcn_mfma_f32_16x16x32_bf16(
                        af[mf][kc], bf[nf][kc], acc[mf][nf], 0, 0, 0);
    };
    auto epi_pair = [&](const float* b1, const float* b2, unsigned short* dst) {
        #pragma unroll
        for (int nf = 0; nf < 2; ++nf) {
            int h = n0 + nf * 16 + (lane & 15);
            float b1v = b1[h], b2v = b2[h];
            #pragma unroll
            for (int mf = 0; mf < 4; ++mf) {
                int abase = a0 + mf * 16 + ((lane >> 4) << 2);
                unsigned long long pv64 = 0;
                #pragma unroll
                for (int j = 0; j < 4; ++j) {
                    float pv = acc0[mf][nf][j] + b1v;
                    float gv = acc1[mf][nf][j] + b2v;
                    float mk = src_mask[abase + j] * smb;
                    unsigned long long q = f2b(pv * mk * sigmoidf_(gv));
                    pv64 |= q << (16 * j);
                }
                *(unsigned long long*)(dst + (size_t)h * NN + (size_t)b * NSEQ + abase) = pv64;
            }
        }
    };

    // matrix order: 0=wl(acc0) 1=wlg(acc1) -> left; 2=wr 3=wrg -> right; 4=wog
    loadB(bfA, 0);
    loadB(bfB, 1);
    mmat(acc0, bfA);
    loadB(bfA, 2);
    mmat(acc1, bfB);
    loadB(bfB, 3);
    epi_pair(bl, blg, left_t);
    mmat(acc0, bfA);
    loadB(bfA, 4);
    mmat(acc1, bfB);
    epi_pair(br, brg, right_t);
    mmat(acc0, bfA);
    // og epilogue: [r][h] natural layout
    #pragma unroll
    for (int nf = 0; nf < 2; ++nf) {
        int h = n0 + nf * 16 + (lane & 15);
        float bv = bog[h];
        #pragma unroll
        for (int mf = 0; mf < 4; ++mf) {
            int abase = a0 + mf * 16 + ((lane >> 4) << 2);
            #pragma unroll
            for (int j = 0; j < 4; ++j) {
                float ov = sigmoidf_(acc0[mf][nf][j] + bv);
                og[((size_t)(abase + j) * NSEQ + b) * DMODEL + h] = f2b(ov);
            }
        }
    }
}

// ---------------------------------------------------------------------------
// Einsum: per d-plane GEMM C[i][j] = sum_k A[i][k]*B[j][k], 128x128 tile, BK=32.
// ---------------------------------------------------------------------------
__global__ __launch_bounds__(256) void k_einsum(
    const unsigned short* __restrict__ lt,
    const unsigned short* __restrict__ rt,
    unsigned short* __restrict__ mid) {
    __shared__ __align__(16) unsigned short As[128 * 40];
    __shared__ __align__(16) unsigned short Bs[128 * 40];
    const int t = threadIdx.x, lane = t & 63, wv = t >> 6;
    const int d = blockIdx.z;
    const int i0 = blockIdx.x * 128, j0 = blockIdx.y * 128;
    const int m0 = (wv >> 1) * 64, n0 = (wv & 1) * 64;
    const unsigned short* Ag = lt + (size_t)d * NN;
    const unsigned short* Bg = rt + (size_t)d * NN;

    f32x4 acc[4][4];
    #pragma unroll
    for (int mf = 0; mf < 4; ++mf)
        #pragma unroll
        for (int nf = 0; nf < 4; ++nf)
            acc[mf][nf] = f32x4{0.f, 0.f, 0.f, 0.f};

    for (int k0 = 0; k0 < NSEQ; k0 += 32) {
        __syncthreads();
        for (int it = 0; it < 2; ++it) {
            int idx = it * 256 + t;
            int row = idx >> 2, c = idx & 3;
            *(short8*)(&As[row * 40 + c * 8]) =
                *(const short8*)(Ag + (size_t)(i0 + row) * NSEQ + k0 + c * 8);
            *(short8*)(&Bs[row * 40 + c * 8]) =
                *(const short8*)(Bg + (size_t)(j0 + row) * NSEQ + k0 + c * 8);
        }
        __syncthreads();
        int ko = (lane >> 4) * 8;
        short8 af[4], bf[4];
        #pragma unroll
        for (int mf = 0; mf < 4; ++mf)
            af[mf] = *(const short8*)(&As[(m0 + mf * 16 + (lane & 15)) * 40 + ko]);
        #pragma unroll
        for (int nf = 0; nf < 4; ++nf)
            bf[nf] = *(const short8*)(&Bs[(n0 + nf * 16 + (lane & 15)) * 40 + ko]);
        #pragma unroll
        for (int mf = 0; mf < 4; ++mf)
            #pragma unroll
            for (int nf = 0; nf < 4; ++nf)
                acc[mf][nf] = __builtin_amdgcn_mfma_f32_16x16x32_bf16(
                    af[mf], bf[nf], acc[mf][nf], 0, 0, 0);
    }
    unsigned short* out = mid + (size_t)d * NN;
    #pragma unroll
    for (int mf = 0; mf < 4; ++mf) {
        int rbase = i0 + m0 + mf * 16 + ((lane >> 4) << 2);
        #pragma unroll
        for (int nf = 0; nf < 4; ++nf) {
            int col = j0 + n0 + nf * 16 + (lane & 15);
            #pragma unroll
            for (int j = 0; j < 4; ++j)
                out[(size_t)(rbase + j) * NSEQ + col] = f2b(acc[mf][nf][j]);
        }
    }
}

// ---------------------------------------------------------------------------
// LN2*gate. Thread = position; whole 128-d row kept in 64 packed VGPRs
// (mid read ONCE, coalesced). Output bounced through LDS for coalesced
// contiguous stores.
// ---------------------------------------------------------------------------
__global__ __launch_bounds__(128) void k_ln2gate(
    const unsigned short* __restrict__ mid,
    const unsigned short* __restrict__ og,
    const float* __restrict__ sc, const float* __restrict__ bi,
    unsigned short* __restrict__ g) {
    __shared__ __align__(16) unsigned short lo[128 * 136];
    const int t = threadIdx.x;
    const size_t p0 = (size_t)blockIdx.x * 128;
    const size_t p = p0 + t;

    unsigned int vals[64];
    float s = 0.f, sq = 0.f;
    #pragma unroll
    for (int d2 = 0; d2 < 64; ++d2) {
        unsigned int a = mid[(size_t)(2 * d2)     * NN + p];
        unsigned int c = mid[(size_t)(2 * d2 + 1) * NN + p];
        vals[d2] = a | (c << 16);
        float fa = b2f((unsigned short)a), fc = b2f((unsigned short)c);
        s += fa + fc; sq += fa * fa + fc * fc;
    }
    float mean = s * (1.f / 128.f);
    float var  = sq * (1.f / 128.f) - mean * mean;
    float inv  = rsqrtf(var + 1e-6f);
    #pragma unroll
    for (int c = 0; c < 16; ++c) {
        short8 ov = *(const short8*)(og + p * DMODEL + c * 8);
        short8 r8;
        #pragma unroll
        for (int e = 0; e < 8; ++e) {
            int d = c * 8 + e;
            unsigned int w = vals[d >> 1];
            float v = b2f((unsigned short)((d & 1) ? (w >> 16) : (w & 0xffff)));
            float y = (v - mean) * inv * sc[d] + bi[d];
            r8[e] = (short)f2b(y * b2f((unsigned short)ov[e]));
        }
        *(short8*)(&lo[t * 136 + c * 8]) = r8;
    }
    __syncthreads();
    #pragma unroll
    for (int i = 0; i < 16; ++i) {
        int idx = i * 128 + t;
        int row = idx >> 4, ch = idx & 15;
        *(short8*)(g + (p0 + row) * DMODEL + ch * 8) =
            *(const short8*)(&lo[row * 136 + ch * 8]);
    }
}

// ---------------------------------------------------------------------------
// Output projection: out = g @ wo + bo (fp32 out). 64-row tiles, full N=128.
// ---------------------------------------------------------------------------
__global__ __launch_bounds__(256) void k_out(
    const unsigned short* __restrict__ g,
    const unsigned short* __restrict__ wt_o,
    const float* __restrict__ bo,
    float* __restrict__ out) {
    __shared__ __align__(16) unsigned short As[64 * 136];
    __shared__ __align__(16) unsigned short Bs[128 * 136];
    const int t = threadIdx.x, lane = t & 63, wv = t >> 6;
    const size_t r0 = (size_t)blockIdx.x * 64;
    const int n0 = wv * 32;
    for (int it = 0; it < 4; ++it) {
        int idx = it * 256 + t;
        int row = idx >> 4, c = idx & 15;
        *(short8*)(&As[row * 136 + c * 8]) =
            *(const short8*)(g + (r0 + row) * DMODEL + c * 8);
    }
    for (int it = 0; it < 8; ++it) {
        int idx = it * 256 + t;
        int h = idx >> 4, c = idx & 15;
        *(short8*)(&Bs[h * 136 + c * 8]) = *(const short8*)(wt_o + h * 128 + c * 8);
    }
    __syncthreads();
    f32x4 acc[4][2];
    #pragma unroll
    for (int mf = 0; mf < 4; ++mf)
        #pragma unroll
        for (int nf = 0; nf < 2; ++nf)
            acc[mf][nf] = f32x4{0.f, 0.f, 0.f, 0.f};
    #pragma unroll
    for (int kc = 0; kc < 4; ++kc) {
        int ko = kc * 32 + (lane >> 4) * 8;
        short8 af[4], bf[2];
        #pragma unroll
        for (int mf = 0; mf < 4; ++mf)
            af[mf] = *(const short8*)(&As[(mf * 16 + (lane & 15)) * 136 + ko]);
        #pragma unroll
        for (int nf = 0; nf < 2; ++nf)
            bf[nf] = *(const short8*)(&Bs[(n0 + nf * 16 + (lane & 15)) * 136 + ko]);
        #pragma unroll
        for (int mf = 0; mf < 4; ++mf)
            #pragma unroll
            for (int nf = 0; nf < 2; ++nf)
                acc[mf][nf] = __builtin_amdgcn_mfma_f32_16x16x32_bf16(
                    af[mf], bf[nf], acc[mf][nf], 0, 0, 0);
    }
    #pragma unroll
    for (int nf = 0; nf < 2; ++nf) {
        int n = n0 + nf * 16 + (lane & 15);
        float bv = bo[n];
        #pragma unroll
        for (int mf = 0; mf < 4; ++mf) {
            int rb = mf * 16 + ((lane >> 4) << 2);
            #pragma unroll
            for (int j = 0; j < 4; ++j)
                out[(r0 + rb + j) * DMODEL + n] = acc[mf][nf][j] + bv;
        }
    }
}

// ---------------------------------------------------------------------------
extern "C" void kernel_launch(void* const* d_in, const int* in_sizes, int n_in,
                              void* d_out, int out_size, void* d_ws, size_t ws_size,
                              hipStream_t stream) {
    const float* x    = (const float*)d_in[0];
    const float* sm   = (const float*)d_in[1];
    const float* ln1s = (const float*)d_in[2];
    const float* ln1b = (const float*)d_in[3];
    const float* wl   = (const float*)d_in[4];
    const float* bl   = (const float*)d_in[5];
    const float* wr   = (const float*)d_in[6];
    const float* br   = (const float*)d_in[7];
    const float* wlg  = (const float*)d_in[8];
    const float* blg  = (const float*)d_in[9];
    const float* wrg  = (const float*)d_in[10];
    const float* brg  = (const float*)d_in[11];
    const float* wog  = (const float*)d_in[12];
    const float* bog  = (const float*)d_in[13];
    const float* ln2s = (const float*)d_in[14];
    const float* ln2b = (const float*)d_in[15];
    const float* wo   = (const float*)d_in[16];
    const float* bo   = (const float*)d_in[17];
    float* out = (float*)d_out;

    // workspace: wt(196608B) | lt | rt | og | mid | g  (5 x 64MB)
    char* ws = (char*)d_ws;
    unsigned short* wt  = (unsigned short*)ws;
    unsigned short* lt  = (unsigned short*)(ws + 196608);
    unsigned short* rt  = (unsigned short*)(ws + 196608 + 1ull * 67108864);
    unsigned short* ogb = (unsigned short*)(ws + 196608 + 2ull * 67108864);
    unsigned short* mid = (unsigned short*)(ws + 196608 + 3ull * 67108864);
    unsigned short* gb  = (unsigned short*)(ws + 196608 + 4ull * 67108864);

    k_wt_all<<<384, 256, 0, stream>>>(wl, wlg, wr, wrg, wog, wo, wt);
    k_proj<<<dim3(8, 512), 256, 0, stream>>>(x, sm, ln1s, ln1b, wt,
                                             bl, blg, br, brg, bog, lt, rt, ogb);
    k_einsum<<<dim3(4, 4, 128), 256, 0, stream>>>(lt, rt, mid);
    k_ln2gate<<<2048, 128, 0, stream>>>(mid, ogb, ln2s, ln2b, gb);
    k_out<<<4096, 256, 0, stream>>>(gb, wt + 5 * 16384, bo, out);
}